// Round 12
// baseline (208.850 us; speedup 1.0000x reference)
//
#include <hip/hip_runtime.h>
#include <math.h>

// Problem constants (from reference setup_inputs)
#define NB     64      // batch
#define N1V    8192    // obj points per batch
#define NPTS   (NB * N1V)
#define NV     778     // recon / gt verts
#define NVP    780     // padded to multiple of 4
#define NQ     195     // target quads
#define SEG1Q  51      // first 51 quads = 204 permuted targets = PRIOR set
#define NFACE  1538
#define NZ     64
#define NPAR   61
#define NPRIOR 204
#define PPT    8       // obj points per thread (rec/gt roles)
#define BIAS   0.0625f // 2|a||t| <= 0.06 < BIAS -> biased rec partials stay >= 0
#define GR     0.005f  // gt_cmap radius

// Single kernel, 4 roles (R9/R11 structure).
#define GT_BLOCKS  256                 // [0,256): (batch, chunk-of-2048) grid range-query
#define REC_BLOCKS 256                 // [256,512)
#define CH_BLOCKS  128                 // [512,640): chamfer (batch, dir)
#define NRM_BLOCKS 64                  // [640,704): per-batch GRID build + normals
#define REC_BASE GT_BLOCKS
#define CH_BASE  (REC_BASE + REC_BLOCKS)
#define NRM_BASE (CH_BASE + CH_BLOCKS)
#define NBLOCKS  (NRM_BASE + NRM_BLOCKS)   // 704
// Deadlock safety: all 704 co-resident. LDS union 18.7KB -> 8 blocks/CU;
// VGPR<=64 -> 8 waves/SIMD. capacity 2048 >> 704.

// ws float layout:
//   [0, NB*NVP*4)   nrm4p[NB][NVP] float4: RAW face-normal sums, PERMUTED
//   acc[16]         2 chamfer, 3 S_cmap, 4 N_cmap, 5 N_gt, 6 N_cons, 7 S_pen,
//                   8 param, 9 kld, 15 ticket
//   flags[384]      [0,256) gt-chunk gc release; [256,320) nrm; [320,384) grid
//   gcA             uchar[NPTS/8] gt-cmap bits        (16384 floats)
//   sorted4         float4[NB][NVP]: gt verts cell-sorted, pre-scaled (-2x,-2y,-2z,|t|^2)
//   gstart          uint[NB][513]: CSR cell offsets (8x8x8 grid, h=0.0125)
#define ACC_OFF    (NB * NVP * 4)
#define FLAGS_OFF  (ACC_OFF + 16)
#define NFLAGS     384
#define GC_OFF     (FLAGS_OFF + NFLAGS)
#define SORT4_OFF  (GC_OFF + NPTS / 8 / 4)       // +16384 floats
#define GSTART_OFF (SORT4_OFF + NB * NVP * 4)

// ---- compile-time prior permutation (pure function of the static index list) ----
static constexpr int PRIOR_LIST[NPRIOR] = {
  697,698,699,700,712,713,714,715,737,738,739,740,741,743,744,745,746,748,749,750,
  753,754,755,756,757,758,759,760,761,762,763,764,765,766,767,768,
  46,47,48,49,164,165,166,167,194,195,223,237,238,280,281,298,301,317,320,323,
  324,325,326,327,328,329,330,331,332,333,340,341,342,343,344,345,346,347,348,349,
  350,351,352,353,354,355,
  356,357,358,359,375,376,386,387,396,397,402,403,413,429,433,434,435,436,437,438,
  439,440,441,442,443,444,452,453,454,455,456,459,460,461,462,463,464,465,466,467,
  468,469,470,471,484,485,486,496,497,506,507,513,514,524,545,546,547,548,549,550,
  551,552,553,555,563,564,565,566,567,570,572,573,574,575,576,577,578,
  580,581,582,583,600,601,602,614,615,624,625,630,631,641,663,664,665,666,667,668,
  670,672,680,681,682,683,684,686,687,688,689,690,691,692,693,694,695,
  73,96,98,99,772,774,775,777
};

struct PermT { unsigned short v[NV]; };
static constexpr PermT make_perm() {
    PermT t{};
    bool mem[NV] = {};
    for (int i = 0; i < NPRIOR; ++i) mem[PRIOR_LIST[i]] = true;
    int a = 0, b = NPRIOR;
    for (int j = 0; j < NV; ++j) {
        if (mem[j]) t.v[a++] = (unsigned short)j;
        else        t.v[b++] = (unsigned short)j;
    }
    return t;
}
__device__ __constant__ PermT c_perm = make_perm();

struct ScanSh { float4 t[NVP]; float red[4]; };
struct GtSh   { float4 t[NVP]; float red[4]; unsigned int start[513]; };
struct NrmSh  { float x[NV], y[NV], z[NV], vnx[NV], vny[NV], vnz[NV]; };
struct GrdSh  { unsigned int hist[513]; unsigned int cur[512]; };
union ShU { ScanSh scan; GtSh gts; NrmSh nrm; GrdSh grd; };

// 8 points per thread = 24 floats = 6 float4
#define LOAD_PTS(ob)                                                          \
    const float4* ob4 = (const float4*)((ob) + (size_t)tid * 24);             \
    float4 q0 = ob4[0], q1 = ob4[1], q2 = ob4[2],                             \
           q3 = ob4[3], q4 = ob4[4], q5 = ob4[5];                             \
    float px[PPT], py[PPT], pz[PPT];                                          \
    px[0]=q0.x; py[0]=q0.y; pz[0]=q0.z;  px[1]=q0.w; py[1]=q1.x; pz[1]=q1.y;  \
    px[2]=q1.z; py[2]=q1.w; pz[2]=q2.x;  px[3]=q2.y; py[3]=q2.z; pz[3]=q2.w;  \
    px[4]=q3.x; py[4]=q3.y; pz[4]=q3.z;  px[5]=q3.w; py[5]=q4.x; pz[5]=q4.y;  \
    px[6]=q4.z; py[6]=q4.w; pz[6]=q5.x;  px[7]=q5.y; py[7]=q5.z; pz[7]=q5.w;

__device__ __forceinline__ float min3f(float a, float b, float c) {
    return fminf(fminf(a, b), c);   // folds to v_min3_f32
}

// 8^3 grid over [0,0.1]^3, h=0.0125. Monotone: cidx(u)<=cidx(v) for u<=v.
__device__ __forceinline__ int cidx(float v) {
    int c = (int)(v * 80.0f);
    return c < 0 ? 0 : (c > 7 ? 7 : c);
}

__device__ __forceinline__ void spin_wait(unsigned int* f, int tid) {
    if (tid == 0) {
        while (__hip_atomic_load(f, __ATOMIC_ACQUIRE, __HIP_MEMORY_SCOPE_AGENT) == 0u)
            __builtin_amdgcn_s_sleep(2);
    }
    __syncthreads();   // tid0's acquire + barrier orders subsequent reads
}

__global__ __launch_bounds__(256) void k_all(
        const float* __restrict__ obj,   const float* __restrict__ recon,
        const float* __restrict__ gt,    const int*   __restrict__ faces,
        const float* __restrict__ mean,  const float* __restrict__ log_var,
        const float* __restrict__ rp,    const float* __restrict__ xp,
        float4* __restrict__ ws4,        float* __restrict__ acc,
        unsigned int* __restrict__ flags, unsigned char* __restrict__ gcA,
        float4* __restrict__ sorted4,    unsigned int* __restrict__ gstart,
        float* __restrict__ out) {
    __shared__ ShU sh;
    __shared__ unsigned int s_tk;
    __shared__ float s_pk[2];
    int tid = threadIdx.x;
    int blk = blockIdx.x;

    if (blk < GT_BLOCKS) {
        // ============ GT ROLE: grid RANGE QUERY (exact bit: min<thr <=> any cand<thr) ============
        int r = blk, b = r >> 2, chunk = r & 3;
        const float* ob = obj + ((size_t)b * N1V + (size_t)chunk * 2048) * 3;
        LOAD_PTS(ob)   // load points while grid is being built
        if (tid == 0) sh.gts.red[0] = 0.0f;
        spin_wait(&flags[320 + b], tid);   // grid published (~10us; GT not critical path)
        for (int j = tid; j < NV; j += 256) sh.gts.t[j] = sorted4[(size_t)b * NVP + j];
        for (int j = tid; j < 513; j += 256) sh.gts.start[j] = gstart[(size_t)b * 513 + j];
        __syncthreads();

        float lN_gt = 0.0f;
        unsigned int gcbits = 0;
#pragma unroll
        for (int i = 0; i < PPT; ++i) {
            float a2v = px[i]*px[i] + py[i]*py[i] + pz[i]*pz[i];
            int ix0 = cidx(px[i] - GR), ix1 = cidx(px[i] + GR);
            int iy0 = cidx(py[i] - GR), iy1 = cidx(py[i] + GR);
            int iz0 = cidx(pz[i] - GR), iz1 = cidx(pz[i] + GR);
            bool found = false;
#pragma unroll
            for (int cc = 0; cc < 8; ++cc) {
                if (((cc & 1) && ix1 == ix0) || ((cc & 2) && iy1 == iy0) ||
                    ((cc & 4) && iz1 == iz0)) continue;   // skip duplicate cells
                int cx = (cc & 1) ? ix1 : ix0;
                int cy = (cc & 2) ? iy1 : iy0;
                int cz = (cc & 4) ? iz1 : iz0;
                int cell = (cz * 8 + cy) * 8 + cx;
                int s = (int)sh.gts.start[cell], e = (int)sh.gts.start[cell + 1];
                for (int k = s; k < e; ++k) {
                    float4 t = sh.gts.t[k];
                    float part = fmaf(px[i], t.x, fmaf(py[i], t.y, fmaf(pz[i], t.z, t.w)));
                    // identical expr to dense per-target; monotone g => bit == dense bit
                    found |= (sqrtf(fmaxf(a2v + part, 0.0f)) < GR);
                }
            }
            if (found) { lN_gt += 1.0f; gcbits |= (1u << i); }
        }
        gcA[(size_t)r * 256 + tid] = (unsigned char)gcbits;
        atomicAdd(&sh.gts.red[0], lN_gt);
        __syncthreads();      // gc bytes + reduction done
        if (tid == 0) {
            __threadfence();  // publish gc BYTES (non-atomic) before the flag
            __hip_atomic_store(&flags[r], 1u, __ATOMIC_RELEASE, __HIP_MEMORY_SCOPE_AGENT);
            atomicAdd(&acc[5], sh.gts.red[0]);
        }
    } else if (blk < CH_BASE) {
        // ============ REC ROLE: inline perm -2x staging + scan + split epilogue (R11) ============
        int r = blk - REC_BASE, b = r >> 2, chunk = r & 3;
        const float* rb = recon + (size_t)b * NV * 3;
        float4* s_t = sh.scan.t;
        for (int j = tid; j < NVP; j += 256) {
            if (j < NV) {
                int src = c_perm.v[j];
                float x = rb[3*src], y = rb[3*src+1], z = rb[3*src+2];
                s_t[j] = make_float4(-2.0f*x, -2.0f*y, -2.0f*z, x*x + y*y + z*z + BIAS);
            } else s_t[j] = make_float4(0.f, 0.f, 0.f, 1e30f);
        }
        if (tid < 4) sh.scan.red[tid] = 0.0f;
        __syncthreads();

        const float* ob = obj + ((size_t)b * N1V + (size_t)chunk * 2048) * 3;
        LOAD_PTS(ob)
        float m[PPT];
        int q[PPT];
#pragma unroll
        for (int i = 0; i < PPT; ++i) { m[i] = 3.4e38f; q[i] = 0; }
        float mp[PPT];
#pragma unroll 1
        for (int jq = 0; jq < SEG1Q; ++jq) {
            int j = 4 * jq;
            float4 t0 = s_t[j], t1 = s_t[j+1], t2 = s_t[j+2], t3 = s_t[j+3];
#pragma unroll
            for (int i = 0; i < PPT; ++i) {
                float d0 = fmaf(px[i], t0.x, fmaf(py[i], t0.y, fmaf(pz[i], t0.z, t0.w)));
                float d1 = fmaf(px[i], t1.x, fmaf(py[i], t1.y, fmaf(pz[i], t1.z, t1.w)));
                float d2 = fmaf(px[i], t2.x, fmaf(py[i], t2.y, fmaf(pz[i], t2.z, t2.w)));
                float d3 = fmaf(px[i], t3.x, fmaf(py[i], t3.y, fmaf(pz[i], t3.z, t3.w)));
                float u  = min3f(d0, d1, d2);
                float mn = min3f(u, d3, m[i]);
                q[i] = (mn < m[i]) ? jq : q[i];
                m[i] = mn;
            }
        }
#pragma unroll
        for (int i = 0; i < PPT; ++i) mp[i] = m[i];   // prior min snapshot
#pragma unroll 1
        for (int jq = SEG1Q; jq < NQ; ++jq) {
            int j = 4 * jq;
            float4 t0 = s_t[j], t1 = s_t[j+1], t2 = s_t[j+2], t3 = s_t[j+3];
#pragma unroll
            for (int i = 0; i < PPT; ++i) {
                float d0 = fmaf(px[i], t0.x, fmaf(py[i], t0.y, fmaf(pz[i], t0.z, t0.w)));
                float d1 = fmaf(px[i], t1.x, fmaf(py[i], t1.y, fmaf(pz[i], t1.z, t1.w)));
                float d2 = fmaf(px[i], t2.x, fmaf(py[i], t2.y, fmaf(pz[i], t2.z, t2.w)));
                float d3 = fmaf(px[i], t3.x, fmaf(py[i], t3.y, fmaf(pz[i], t3.z, t3.w)));
                float u  = min3f(d0, d1, d2);
                float mn = min3f(u, d3, m[i]);
                q[i] = (mn < m[i]) ? jq : q[i];
                m[i] = mn;
            }
        }
        // ---- epilogue pass 1: everything except the normal gather ----
        float lS_cmap = 0.0f, lN_cmap = 0.0f;
        unsigned int rcbits = 0;
        int js[PPT]; float drecs[PPT];
#pragma unroll
        for (int i = 0; i < PPT; ++i) {
            float a2 = px[i]*px[i] + py[i]*py[i] + pz[i]*pz[i];
            float drec = fmaxf(a2 + (m[i]  - BIAS), 0.0f);
            float dpri = fmaxf(a2 + (mp[i] - BIAS), 0.0f);
            bool cm = drec < 1e-4f;
            bool rc = sqrtf(drec) < 0.005f;
            if (cm) { lS_cmap += dpri; lN_cmap += 1.0f; }
            if (rc) rcbits |= (1u << i);
            // winning-quad re-eval from LDS for jstar (bit-identical fma chain)
            int jr = 4 * q[i];
            float4 t0 = s_t[jr], t1 = s_t[jr+1], t2 = s_t[jr+2], t3 = s_t[jr+3];
            float d0 = fmaf(px[i], t0.x, fmaf(py[i], t0.y, fmaf(pz[i], t0.z, t0.w)));
            float d1 = fmaf(px[i], t1.x, fmaf(py[i], t1.y, fmaf(pz[i], t1.z, t1.w)));
            float d2 = fmaf(px[i], t2.x, fmaf(py[i], t2.y, fmaf(pz[i], t2.z, t2.w)));
            float d3 = fmaf(px[i], t3.x, fmaf(py[i], t3.y, fmaf(pz[i], t3.z, t3.w)));
            float mmin = fminf(fminf(d0, d1), fminf(d2, d3));
            int off = (d0 == mmin) ? 0 : ((d1 == mmin) ? 1 : ((d2 == mmin) ? 2 : 3));
            js[i] = jr + off;
            drecs[i] = drec;
        }
        atomicAdd(&sh.scan.red[0], lS_cmap);
        atomicAdd(&sh.scan.red[1], lN_cmap);
        // ---- wait for normals (done early) and gt twin ----
        spin_wait(&flags[256 + b], tid);   // nrm4p published
        spin_wait(&flags[r], tid);         // gc bytes published
        const float4* nrm4p = ws4 + (size_t)b * NVP;
        float lS_pen = 0.0f;
#pragma unroll
        for (int i = 0; i < PPT; ++i) {
            float4 tS = s_t[js[i]];     // stored (-2x,-2y,-2z,*): recover via exact -0.5x
            float4 nr = nrm4p[js[i]];   // RAW normal sum: only sign of ddot matters
            float ddot = (-0.5f*tS.x - px[i]) * nr.x + (-0.5f*tS.y - py[i]) * nr.y
                       + (-0.5f*tS.z - pz[i]) * nr.z;
            if (ddot > 0.0f) lS_pen += drecs[i];
        }
        unsigned int gcb = gcA[(size_t)r * 256 + tid];
        float lcons = (float)__popc(rcbits & gcb);
        atomicAdd(&sh.scan.red[2], lS_pen);
        atomicAdd(&sh.scan.red[3], lcons);
        __syncthreads();
        if (tid == 0) atomicAdd(&acc[3], sh.scan.red[0]);
        if (tid == 1) atomicAdd(&acc[4], sh.scan.red[1]);
        if (tid == 2) atomicAdd(&acc[7], sh.scan.red[2]);
        if (tid == 3) atomicAdd(&acc[6], sh.scan.red[3]);
    } else if (blk < NRM_BASE) {
        // ============ CHAMFER ROLE: -2x staged target, raw source (R11) ============
        int c   = blk - CH_BASE;
        int b   = c >> 1;
        int dir = c & 1;           // 0: rec->gt, 1: gt->rec
        const float* rb = recon + (size_t)b * NV * 3;
        const float* gb = gt    + (size_t)b * NV * 3;
        const float* tb = dir ? rb : gb;   // target side
        const float* sb = dir ? gb : rb;   // source side
        float4* s_t = sh.scan.t;
        for (int j = tid; j < NVP; j += 256) {
            if (j < NV) {
                float x = tb[3*j], y = tb[3*j+1], z = tb[3*j+2];
                float w = x*x + y*y + z*z;
                if (dir) w += BIAS;        // rec side carries BIAS
                s_t[j] = make_float4(-2.0f*x, -2.0f*y, -2.0f*z, w);
            } else s_t[j] = make_float4(0.f, 0.f, 0.f, 1e30f);
        }
        if (tid == 0) sh.scan.red[0] = 0.0f;
        __syncthreads();

        const int CPT = 4;
        float sx[CPT], sy[CPT], sz[CPT], a2[CPT], m[CPT];
        bool valid[CPT];
#pragma unroll
        for (int k = 0; k < CPT; ++k) {
            int p = tid + 256 * k;
            valid[k] = (p < NV);
            int pp = valid[k] ? p : 0;
            float x = sb[3*pp], y = sb[3*pp+1], z = sb[3*pp+2];
            float w = x*x + y*y + z*z;
            if (!dir) w += BIAS;           // rec side carries BIAS
            sx[k] = x; sy[k] = y; sz[k] = z;
            a2[k] = w;
            m[k] = 3.4e38f;
        }
#pragma unroll 1
        for (int j = 0; j < NVP; j += 4) {
            float4 t0 = s_t[j], t1 = s_t[j+1], t2 = s_t[j+2], t3 = s_t[j+3];
#pragma unroll
            for (int k = 0; k < CPT; ++k) {
                float d0 = fmaf(sx[k], t0.x, fmaf(sy[k], t0.y, fmaf(sz[k], t0.z, t0.w)));
                float d1 = fmaf(sx[k], t1.x, fmaf(sy[k], t1.y, fmaf(sz[k], t1.z, t1.w)));
                float d2 = fmaf(sx[k], t2.x, fmaf(sy[k], t2.y, fmaf(sz[k], t2.z, t2.w)));
                float d3 = fmaf(sx[k], t3.x, fmaf(sy[k], t3.y, fmaf(sz[k], t3.z, t3.w)));
                float u = min3f(d0, d1, d2);
                m[k] = min3f(u, d3, m[k]);
            }
        }
        float local = 0.0f;
#pragma unroll
        for (int k = 0; k < CPT; ++k)
            if (valid[k]) local += fmaxf(a2[k] + m[k] - BIAS, 0.0f);
        atomicAdd(&sh.scan.red[0], local);
        __syncthreads();
        if (tid == 0) atomicAdd(&acc[2], sh.scan.red[0]);
    } else {
        // ============ NRM ROLE: grid build -> flag, then normals -> flag ============
        int b = blk - NRM_BASE;
        const float* gb = gt    + (size_t)b * NV * 3;
        const float* rb = recon + (size_t)b * NV * 3;
        // ---- phase A: GT cell grid (8^3 CSR), targets pre-scaled like dense staging ----
        for (int j = tid; j < 513; j += 256) sh.grd.hist[j] = 0u;
        __syncthreads();
        for (int v = tid; v < NV; v += 256) {
            float x = gb[3*v], y = gb[3*v+1], z = gb[3*v+2];
            int cell = (cidx(z) * 8 + cidx(y)) * 8 + cidx(x);
            atomicAdd(&sh.grd.hist[cell], 1u);
        }
        __syncthreads();
        if (tid == 0) {                      // simple serial exclusive scan (512 cells)
            unsigned int run = 0;
            for (int c2 = 0; c2 < 512; ++c2) {
                unsigned int t = sh.grd.hist[c2];
                sh.grd.hist[c2] = run; run += t;
            }
            sh.grd.hist[512] = run;          // = NV
        }
        __syncthreads();
        for (int j = tid; j < 512; j += 256) sh.grd.cur[j] = sh.grd.hist[j];
        for (int j = tid; j < 513; j += 256) gstart[(size_t)b * 513 + j] = sh.grd.hist[j];
        __syncthreads();
        for (int v = tid; v < NV; v += 256) {
            float x = gb[3*v], y = gb[3*v+1], z = gb[3*v+2];
            int cell = (cidx(z) * 8 + cidx(y)) * 8 + cidx(x);
            unsigned int pos = atomicAdd(&sh.grd.cur[cell], 1u);
            sorted4[(size_t)b * NVP + pos] = make_float4(-2.0f*x, -2.0f*y, -2.0f*z,
                                                         x*x + y*y + z*z);
        }
        __syncthreads();
        if (tid == 0) {
            __threadfence();
            __hip_atomic_store(&flags[320 + b], 1u, __ATOMIC_RELEASE, __HIP_MEMORY_SCOPE_AGENT);
        }
        __syncthreads();
        // ---- phase B: raw face-normal sums -> nrm4p (R11) ----
        for (int j = tid; j < NV; j += 256) {
            sh.nrm.x[j] = rb[3*j]; sh.nrm.y[j] = rb[3*j+1]; sh.nrm.z[j] = rb[3*j+2];
            sh.nrm.vnx[j] = 0.0f; sh.nrm.vny[j] = 0.0f; sh.nrm.vnz[j] = 0.0f;
        }
        __syncthreads();
        for (int f = tid; f < NFACE; f += 256) {
            int i0 = faces[3*f], i1 = faces[3*f+1], i2 = faces[3*f+2];
            float p0x = sh.nrm.x[i0], p0y = sh.nrm.y[i0], p0z = sh.nrm.z[i0];
            float e1x = sh.nrm.x[i1] - p0x, e1y = sh.nrm.y[i1] - p0y, e1z = sh.nrm.z[i1] - p0z;
            float e2x = sh.nrm.x[i2] - p0x, e2y = sh.nrm.y[i2] - p0y, e2z = sh.nrm.z[i2] - p0z;
            float fx = e1y * e2z - e1z * e2y;
            float fy = e1z * e2x - e1x * e2z;
            float fz = e1x * e2y - e1y * e2x;
            atomicAdd(&sh.nrm.vnx[i0], fx); atomicAdd(&sh.nrm.vny[i0], fy); atomicAdd(&sh.nrm.vnz[i0], fz);
            atomicAdd(&sh.nrm.vnx[i1], fx); atomicAdd(&sh.nrm.vny[i1], fy); atomicAdd(&sh.nrm.vnz[i1], fz);
            atomicAdd(&sh.nrm.vnx[i2], fx); atomicAdd(&sh.nrm.vny[i2], fy); atomicAdd(&sh.nrm.vnz[i2], fz);
        }
        __syncthreads();
        float4* nrm4p = ws4 + (size_t)b * NVP;
        for (int j = tid; j < NVP; j += 256) {
            if (j < NV) {
                int src = c_perm.v[j];
                nrm4p[j] = make_float4(sh.nrm.vnx[src], sh.nrm.vny[src], sh.nrm.vnz[src], 0.0f);
            } else nrm4p[j] = make_float4(0.f, 0.f, 1.f, 0.0f);
        }
        __syncthreads();   // all nrm4p stores issued block-wide
        if (tid == 0) {
            __threadfence();  // publish nrm4p BYTES (non-atomic) before the flag
            __hip_atomic_store(&flags[256 + b], 1u, __ATOMIC_RELEASE, __HIP_MEMORY_SCOPE_AGENT);
        }
        if (b == 0) {
            // ---- param + KLD on the side (long before any consumer) ----
            if (tid < 2) s_pk[tid] = 0.0f;
            __syncthreads();
            float s_param = 0.0f, s_kld = 0.0f;
            for (int i = tid; i < NB * NPAR; i += 256) {
                float d = rp[i] - xp[i];
                s_param += d * d;
            }
            for (int i = tid; i < NB * NZ; i += 256) {
                float mv = mean[i], lv = log_var[i];
                s_kld += 1.0f + lv - mv * mv - expf(lv);
            }
            atomicAdd(&s_pk[0], s_param);
            atomicAdd(&s_pk[1], s_kld);
            __syncthreads();
            if (tid == 0) { atomicAdd(&acc[8], s_pk[0]); atomicAdd(&acc[9], s_pk[1]); }
        }
    }

    // ============ TICKET + FORMULA (vmcnt-ordered; no per-block L2 writeback) ============
    __syncthreads();   // block's global atomics all issued
    if (tid == 0) {
        asm volatile("s_waitcnt vmcnt(0)" ::: "memory");
        s_tk = atomicAdd((unsigned int*)&acc[15], 1u);
    }
    __syncthreads();
    if (s_tk == NBLOCKS - 1 && tid == 0) {
        __threadfence();                 // acquire (single block, negligible)
        const float fB = 64.0f;
        float a2v = __hip_atomic_load(&acc[2], __ATOMIC_RELAXED, __HIP_MEMORY_SCOPE_AGENT);
        float a3  = __hip_atomic_load(&acc[3], __ATOMIC_RELAXED, __HIP_MEMORY_SCOPE_AGENT);
        float a4  = __hip_atomic_load(&acc[4], __ATOMIC_RELAXED, __HIP_MEMORY_SCOPE_AGENT);
        float a5  = __hip_atomic_load(&acc[5], __ATOMIC_RELAXED, __HIP_MEMORY_SCOPE_AGENT);
        float a6  = __hip_atomic_load(&acc[6], __ATOMIC_RELAXED, __HIP_MEMORY_SCOPE_AGENT);
        float a7  = __hip_atomic_load(&acc[7], __ATOMIC_RELAXED, __HIP_MEMORY_SCOPE_AGENT);
        float a8  = __hip_atomic_load(&acc[8], __ATOMIC_RELAXED, __HIP_MEMORY_SCOPE_AGENT);
        float a9  = __hip_atomic_load(&acc[9], __ATOMIC_RELAXED, __HIP_MEMORY_SCOPE_AGENT);
        float param_loss  = a8 / fB;
        float KLD         = -0.5f * a9 / fB * 10.0f;
        float recon_loss  = a2v / fB;
        float cmap_loss   = 3000.0f * a3 / (fB * a4);
        float consistency = -5.0f * a6 / (a5 + 0.0001f);
        float penetr      = 100.0f * a7 / fB;
        out[0] = (recon_loss + KLD) + 0.1f * param_loss + 1000.0f * cmap_loss
               + 10.0f * consistency + 10.0f * penetr;
    }
}

extern "C" void kernel_launch(void* const* d_in, const int* in_sizes, int n_in,
                              void* d_out, int out_size, void* d_ws, size_t ws_size,
                              hipStream_t stream) {
    (void)in_sizes; (void)n_in; (void)out_size; (void)ws_size;
    const float* obj     = (const float*)d_in[0];
    const float* recon   = (const float*)d_in[1];
    const float* gt      = (const float*)d_in[2];
    const float* mean    = (const float*)d_in[3];
    const float* log_var = (const float*)d_in[4];
    const float* rp      = (const float*)d_in[5];
    const float* xp      = (const float*)d_in[6];
    const int*   faces   = (const int*)d_in[7];
    float* wsf = (float*)d_ws;
    float4* ws4 = (float4*)d_ws;
    float* acc = wsf + ACC_OFF;
    unsigned int* flags = (unsigned int*)(wsf + FLAGS_OFF);
    unsigned char* gcA  = (unsigned char*)(wsf + GC_OFF);
    float4* sorted4     = (float4*)(wsf + SORT4_OFF);
    unsigned int* gstart = (unsigned int*)(wsf + GSTART_OFF);
    float* out = (float*)d_out;

    hipMemsetAsync(acc, 0, (16 + NFLAGS) * sizeof(float), stream);
    k_all<<<NBLOCKS, 256, 0, stream>>>(obj, recon, gt, faces, mean, log_var,
                                       rp, xp, ws4, acc, flags, gcA,
                                       sorted4, gstart, out);
}

// Round 13
// 163.563 us; speedup vs baseline: 1.2769x; 1.2769x over previous
//
#include <hip/hip_runtime.h>
#include <math.h>

// Problem constants (from reference setup_inputs)
#define NB     64      // batch
#define N1V    8192    // obj points per batch
#define NPTS   (NB * N1V)
#define NV     778     // recon / gt verts
#define NVP    780     // padded to multiple of 4
#define NQ     195     // target quads
#define SEG1Q  51      // first 51 quads = 204 permuted targets = PRIOR set
#define NFACE  1538
#define NZ     64
#define NPAR   61
#define NPRIOR 204
#define PPT    8       // obj points per thread (rec/gt roles)
#define BIAS   0.0625f // 2|a||t| <= 0.06 < BIAS -> biased rec partials stay >= 0

// Single kernel, 4 roles (R11 structure, packed-fp32 pairs in scan loops).
#define GT_BLOCKS  256                 // [0,256): (batch, chunk-of-2048)
#define REC_BLOCKS 256                 // [256,512)
#define CH_BLOCKS  128                 // [512,640): chamfer (batch, dir)
#define NRM_BLOCKS 64                  // [640,704): per-batch normals -> ws
#define REC_BASE GT_BLOCKS
#define CH_BASE  (REC_BASE + REC_BLOCKS)
#define NRM_BASE (CH_BASE + CH_BLOCKS)
#define NBLOCKS  (NRM_BASE + NRM_BLOCKS)   // 704
// Deadlock safety: all 704 co-resident. LDS 18.7KB -> 8 blocks/CU; VGPR<=64 ->
// 8 waves/SIMD. capacity 2048 >> 704.

// ws float layout (R11):
//   [0, NB*NVP*4)  nrm4p[NB][NVP] float4: RAW face-normal sums, PERMUTED
//   acc[16]        2 chamfer, 3 S_cmap, 4 N_cmap, 5 N_gt, 6 N_cons, 7 S_pen,
//                  8 param, 9 kld, 15 ticket
//   flags[320]     [0,256) per gt-chunk gc release; [256,320) per-batch nrm
//   gcA            uchar[NPTS/8] gt-cmap bits
#define ACC_OFF   (NB * NVP * 4)
#define FLAGS_OFF (ACC_OFF + 16)
#define NFLAGS    320
#define GC_OFF    (FLAGS_OFF + NFLAGS)

// ---- compile-time prior permutation (pure function of the static index list) ----
static constexpr int PRIOR_LIST[NPRIOR] = {
  697,698,699,700,712,713,714,715,737,738,739,740,741,743,744,745,746,748,749,750,
  753,754,755,756,757,758,759,760,761,762,763,764,765,766,767,768,
  46,47,48,49,164,165,166,167,194,195,223,237,238,280,281,298,301,317,320,323,
  324,325,326,327,328,329,330,331,332,333,340,341,342,343,344,345,346,347,348,349,
  350,351,352,353,354,355,
  356,357,358,359,375,376,386,387,396,397,402,403,413,429,433,434,435,436,437,438,
  439,440,441,442,443,444,452,453,454,455,456,459,460,461,462,463,464,465,466,467,
  468,469,470,471,484,485,486,496,497,506,507,513,514,524,545,546,547,548,549,550,
  551,552,553,555,563,564,565,566,567,570,572,573,574,575,576,577,578,
  580,581,582,583,600,601,602,614,615,624,625,630,631,641,663,664,665,666,667,668,
  670,672,680,681,682,683,684,686,687,688,689,690,691,692,693,694,695,
  73,96,98,99,772,774,775,777
};

struct PermT { unsigned short v[NV]; };
static constexpr PermT make_perm() {
    PermT t{};
    bool mem[NV] = {};
    for (int i = 0; i < NPRIOR; ++i) mem[PRIOR_LIST[i]] = true;
    int a = 0, b = NPRIOR;
    for (int j = 0; j < NV; ++j) {
        if (mem[j]) t.v[a++] = (unsigned short)j;
        else        t.v[b++] = (unsigned short)j;
    }
    return t;
}
__device__ __constant__ PermT c_perm = make_perm();

struct ScanSh { float4 t[NVP]; float red[4]; };
struct NrmSh  { float x[NV], y[NV], z[NV], vnx[NV], vny[NV], vnz[NV]; };
union ShU { ScanSh scan; NrmSh nrm; };

// ---- packed fp32 pairs: v2f fma lowers to v_pk_fma_f32 on gfx950 ----
typedef float v2f __attribute__((ext_vector_type(2)));
__device__ __forceinline__ v2f fma2(v2f a, float b, v2f c) {
    return __builtin_elementwise_fma(a, (v2f){b, b}, c);
}
// 4 distances (one quad) for a point-pair h; t* are wave-uniform targets
#define QUAD_D(h, t0, t1, t2, t3)                                             \
    v2f d0 = fma2(Px[h], (t0).x, fma2(Py[h], (t0).y, fma2(Pz[h], (t0).z, (v2f){(t0).w,(t0).w}))); \
    v2f d1 = fma2(Px[h], (t1).x, fma2(Py[h], (t1).y, fma2(Pz[h], (t1).z, (v2f){(t1).w,(t1).w}))); \
    v2f d2 = fma2(Px[h], (t2).x, fma2(Py[h], (t2).y, fma2(Pz[h], (t2).z, (v2f){(t2).w,(t2).w}))); \
    v2f d3 = fma2(Px[h], (t3).x, fma2(Py[h], (t3).y, fma2(Pz[h], (t3).z, (v2f){(t3).w,(t3).w})));

// 8 points per thread = 24 floats = 6 float4, packed into 4 (x,y,z) pairs
#define LOAD_PTS(ob)                                                          \
    const float4* ob4 = (const float4*)((ob) + (size_t)tid * 24);             \
    float4 q0 = ob4[0], q1 = ob4[1], q2 = ob4[2],                             \
           q3 = ob4[3], q4 = ob4[4], q5 = ob4[5];                             \
    v2f Px[4], Py[4], Pz[4];                                                  \
    Px[0] = (v2f){q0.x, q0.w}; Py[0] = (v2f){q0.y, q1.x}; Pz[0] = (v2f){q0.z, q1.y}; \
    Px[1] = (v2f){q1.z, q2.y}; Py[1] = (v2f){q1.w, q2.z}; Pz[1] = (v2f){q2.x, q2.w}; \
    Px[2] = (v2f){q3.x, q3.w}; Py[2] = (v2f){q3.y, q4.x}; Pz[2] = (v2f){q3.z, q4.y}; \
    Px[3] = (v2f){q4.z, q5.y}; Py[3] = (v2f){q4.w, q5.z}; Pz[3] = (v2f){q5.x, q5.w};

#define PX(i) Px[(i) >> 1][(i) & 1]
#define PY(i) Py[(i) >> 1][(i) & 1]
#define PZ(i) Pz[(i) >> 1][(i) & 1]

__device__ __forceinline__ float min3f(float a, float b, float c) {
    return fminf(fminf(a, b), c);   // folds to v_min3_f32
}

__device__ __forceinline__ void spin_wait(unsigned int* f, int tid) {
    if (tid == 0) {
        while (__hip_atomic_load(f, __ATOMIC_ACQUIRE, __HIP_MEMORY_SCOPE_AGENT) == 0u)
            __builtin_amdgcn_s_sleep(2);
    }
    __syncthreads();   // tid0's acquire + barrier orders subsequent reads
}

// Targets staged PRE-SCALED: s_t = (-2x, -2y, -2z, |t|^2 (+BIAS for rec)).
// d = pk_fma(Px, t.x, pk_fma(Py, t.y, pk_fma(Pz, t.z, t.w))) -- per-half IEEE
// fma, bit-identical to R11's scalar fmaf chain.

__global__ __launch_bounds__(256) void k_all(
        const float* __restrict__ obj,   const float* __restrict__ recon,
        const float* __restrict__ gt,    const int*   __restrict__ faces,
        const float* __restrict__ mean,  const float* __restrict__ log_var,
        const float* __restrict__ rp,    const float* __restrict__ xp,
        float4* __restrict__ ws4,        float* __restrict__ acc,
        unsigned int* __restrict__ flags, unsigned char* __restrict__ gcA,
        float* __restrict__ out) {
    __shared__ ShU sh;
    __shared__ unsigned int s_tk;
    __shared__ float s_pk[2];
    int tid = threadIdx.x;
    int blk = blockIdx.x;

    if (blk < GT_BLOCKS) {
        // ============ GT ROLE: inline -2x transform + packed min scan + gc bits ============
        int r = blk, b = r >> 2, chunk = r & 3;
        const float* gb = gt + (size_t)b * NV * 3;
        float4* s_t = sh.scan.t;
        for (int j = tid; j < NVP; j += 256) {
            if (j < NV) {
                float x = gb[3*j], y = gb[3*j+1], z = gb[3*j+2];
                s_t[j] = make_float4(-2.0f*x, -2.0f*y, -2.0f*z, x*x + y*y + z*z);
            } else s_t[j] = make_float4(0.f, 0.f, 0.f, 1e30f);
        }
        if (tid == 0) sh.scan.red[0] = 0.0f;
        __syncthreads();

        const float* ob = obj + ((size_t)b * N1V + (size_t)chunk * 2048) * 3;
        LOAD_PTS(ob)
        float mgt[PPT];
#pragma unroll
        for (int i = 0; i < PPT; ++i) mgt[i] = 3.4e38f;
#pragma unroll 1
        for (int jq = 0; jq < NQ; ++jq) {
            int j = 4 * jq;
            float4 t0 = s_t[j], t1 = s_t[j+1], t2 = s_t[j+2], t3 = s_t[j+3];
#pragma unroll
            for (int h = 0; h < 4; ++h) {
                QUAD_D(h, t0, t1, t2, t3)
#pragma unroll
                for (int c = 0; c < 2; ++c) {
                    int i = 2*h + c;
                    float u = min3f(d0[c], d1[c], d2[c]);
                    mgt[i] = min3f(u, d3[c], mgt[i]);
                }
            }
        }
        float lN_gt = 0.0f;
        unsigned int gcbits = 0;
#pragma unroll
        for (int i = 0; i < PPT; ++i) {
            float a2 = PX(i)*PX(i) + PY(i)*PY(i) + PZ(i)*PZ(i);
            float dgt = fmaxf(a2 + mgt[i], 0.0f);
            if (sqrtf(dgt) < 0.005f) { lN_gt += 1.0f; gcbits |= (1u << i); }
        }
        gcA[(size_t)r * 256 + tid] = (unsigned char)gcbits;
        atomicAdd(&sh.scan.red[0], lN_gt);
        __syncthreads();      // gc bytes + reduction done
        if (tid == 0) {
            __threadfence();  // publish gc BYTES (non-atomic) before the flag
            __hip_atomic_store(&flags[r], 1u, __ATOMIC_RELEASE, __HIP_MEMORY_SCOPE_AGENT);
            atomicAdd(&acc[5], sh.scan.red[0]);
        }
    } else if (blk < CH_BASE) {
        // ============ REC ROLE: perm -2x staging + packed scan + split epilogue ============
        int r = blk - REC_BASE, b = r >> 2, chunk = r & 3;
        const float* rb = recon + (size_t)b * NV * 3;
        float4* s_t = sh.scan.t;
        for (int j = tid; j < NVP; j += 256) {
            if (j < NV) {
                int src = c_perm.v[j];
                float x = rb[3*src], y = rb[3*src+1], z = rb[3*src+2];
                s_t[j] = make_float4(-2.0f*x, -2.0f*y, -2.0f*z, x*x + y*y + z*z + BIAS);
            } else s_t[j] = make_float4(0.f, 0.f, 0.f, 1e30f);
        }
        if (tid < 4) sh.scan.red[tid] = 0.0f;
        __syncthreads();

        const float* ob = obj + ((size_t)b * N1V + (size_t)chunk * 2048) * 3;
        LOAD_PTS(ob)
        float m[PPT];
        int q[PPT];
#pragma unroll
        for (int i = 0; i < PPT; ++i) { m[i] = 3.4e38f; q[i] = 0; }
        float mp[PPT];
#pragma unroll 1
        for (int jq = 0; jq < SEG1Q; ++jq) {
            int j = 4 * jq;
            float4 t0 = s_t[j], t1 = s_t[j+1], t2 = s_t[j+2], t3 = s_t[j+3];
#pragma unroll
            for (int h = 0; h < 4; ++h) {
                QUAD_D(h, t0, t1, t2, t3)
#pragma unroll
                for (int c = 0; c < 2; ++c) {
                    int i = 2*h + c;
                    float u  = min3f(d0[c], d1[c], d2[c]);
                    float mn = min3f(u, d3[c], m[i]);
                    q[i] = (mn < m[i]) ? jq : q[i];
                    m[i] = mn;
                }
            }
        }
#pragma unroll
        for (int i = 0; i < PPT; ++i) mp[i] = m[i];   // prior min snapshot
#pragma unroll 1
        for (int jq = SEG1Q; jq < NQ; ++jq) {
            int j = 4 * jq;
            float4 t0 = s_t[j], t1 = s_t[j+1], t2 = s_t[j+2], t3 = s_t[j+3];
#pragma unroll
            for (int h = 0; h < 4; ++h) {
                QUAD_D(h, t0, t1, t2, t3)
#pragma unroll
                for (int c = 0; c < 2; ++c) {
                    int i = 2*h + c;
                    float u  = min3f(d0[c], d1[c], d2[c]);
                    float mn = min3f(u, d3[c], m[i]);
                    q[i] = (mn < m[i]) ? jq : q[i];
                    m[i] = mn;
                }
            }
        }
        // ---- epilogue pass 1: everything except the normal gather ----
        float lS_cmap = 0.0f, lN_cmap = 0.0f;
        unsigned int rcbits = 0;
        int js[PPT]; float drecs[PPT];
#pragma unroll
        for (int i = 0; i < PPT; ++i) {
            float a2 = PX(i)*PX(i) + PY(i)*PY(i) + PZ(i)*PZ(i);
            float drec = fmaxf(a2 + (m[i]  - BIAS), 0.0f);
            float dpri = fmaxf(a2 + (mp[i] - BIAS), 0.0f);
            bool cm = drec < 1e-4f;
            bool rc = sqrtf(drec) < 0.005f;
            if (cm) { lS_cmap += dpri; lN_cmap += 1.0f; }
            if (rc) rcbits |= (1u << i);
            // winning-quad re-eval from LDS for jstar (scalar fmaf == pk_fma half)
            int jr = 4 * q[i];
            float4 t0 = s_t[jr], t1 = s_t[jr+1], t2 = s_t[jr+2], t3 = s_t[jr+3];
            float d0 = fmaf(PX(i), t0.x, fmaf(PY(i), t0.y, fmaf(PZ(i), t0.z, t0.w)));
            float d1 = fmaf(PX(i), t1.x, fmaf(PY(i), t1.y, fmaf(PZ(i), t1.z, t1.w)));
            float d2 = fmaf(PX(i), t2.x, fmaf(PY(i), t2.y, fmaf(PZ(i), t2.z, t2.w)));
            float d3 = fmaf(PX(i), t3.x, fmaf(PY(i), t3.y, fmaf(PZ(i), t3.z, t3.w)));
            float mmin = fminf(fminf(d0, d1), fminf(d2, d3));
            int off = (d0 == mmin) ? 0 : ((d1 == mmin) ? 1 : ((d2 == mmin) ? 2 : 3));
            js[i] = jr + off;
            drecs[i] = drec;
        }
        atomicAdd(&sh.scan.red[0], lS_cmap);
        atomicAdd(&sh.scan.red[1], lN_cmap);
        // ---- wait for normals (done early) and gt twin ----
        spin_wait(&flags[256 + b], tid);   // nrm4p published
        spin_wait(&flags[r], tid);         // gc bytes published
        const float4* nrm4p = ws4 + (size_t)b * NVP;
        float lS_pen = 0.0f;
#pragma unroll
        for (int i = 0; i < PPT; ++i) {
            float4 tS = s_t[js[i]];     // stored (-2x,-2y,-2z,*): recover via exact -0.5x
            float4 nr = nrm4p[js[i]];   // RAW normal sum: only sign of ddot matters
            float ddot = (-0.5f*tS.x - PX(i)) * nr.x + (-0.5f*tS.y - PY(i)) * nr.y
                       + (-0.5f*tS.z - PZ(i)) * nr.z;
            if (ddot > 0.0f) lS_pen += drecs[i];
        }
        unsigned int gcb = gcA[(size_t)r * 256 + tid];
        float lcons = (float)__popc(rcbits & gcb);
        atomicAdd(&sh.scan.red[2], lS_pen);
        atomicAdd(&sh.scan.red[3], lcons);
        __syncthreads();
        if (tid == 0) atomicAdd(&acc[3], sh.scan.red[0]);
        if (tid == 1) atomicAdd(&acc[4], sh.scan.red[1]);
        if (tid == 2) atomicAdd(&acc[7], sh.scan.red[2]);
        if (tid == 3) atomicAdd(&acc[6], sh.scan.red[3]);
    } else if (blk < NRM_BASE) {
        // ============ CHAMFER ROLE: packed pairs, -2x staged target ============
        int c   = blk - CH_BASE;
        int b   = c >> 1;
        int dir = c & 1;           // 0: rec->gt, 1: gt->rec
        const float* rb = recon + (size_t)b * NV * 3;
        const float* gb = gt    + (size_t)b * NV * 3;
        const float* tb = dir ? rb : gb;   // target side
        const float* sb = dir ? gb : rb;   // source side
        float4* s_t = sh.scan.t;
        for (int j = tid; j < NVP; j += 256) {
            if (j < NV) {
                float x = tb[3*j], y = tb[3*j+1], z = tb[3*j+2];
                float w = x*x + y*y + z*z;
                if (dir) w += BIAS;        // rec side carries BIAS
                s_t[j] = make_float4(-2.0f*x, -2.0f*y, -2.0f*z, w);
            } else s_t[j] = make_float4(0.f, 0.f, 0.f, 1e30f);
        }
        if (tid == 0) sh.scan.red[0] = 0.0f;
        __syncthreads();

        const int CPT = 4;
        v2f Px[2], Py[2], Pz[2];
        float a2[CPT], m[CPT];
        bool valid[CPT];
#pragma unroll
        for (int k = 0; k < CPT; ++k) {
            int p = tid + 256 * k;
            valid[k] = (p < NV);
            int pp = valid[k] ? p : 0;
            float x = sb[3*pp], y = sb[3*pp+1], z = sb[3*pp+2];
            float w = x*x + y*y + z*z;
            if (!dir) w += BIAS;           // rec side carries BIAS
            Px[k>>1][k&1] = x; Py[k>>1][k&1] = y; Pz[k>>1][k&1] = z;
            a2[k] = w;
            m[k] = 3.4e38f;
        }
#pragma unroll 1
        for (int j = 0; j < NVP; j += 4) {
            float4 t0 = s_t[j], t1 = s_t[j+1], t2 = s_t[j+2], t3 = s_t[j+3];
#pragma unroll
            for (int h = 0; h < 2; ++h) {
                QUAD_D(h, t0, t1, t2, t3)
#pragma unroll
                for (int cc = 0; cc < 2; ++cc) {
                    int k = 2*h + cc;
                    float u = min3f(d0[cc], d1[cc], d2[cc]);
                    m[k] = min3f(u, d3[cc], m[k]);
                }
            }
        }
        float local = 0.0f;
#pragma unroll
        for (int k = 0; k < CPT; ++k)
            if (valid[k]) local += fmaxf(a2[k] + m[k] - BIAS, 0.0f);
        atomicAdd(&sh.scan.red[0], local);
        __syncthreads();
        if (tid == 0) atomicAdd(&acc[2], sh.scan.red[0]);
    } else {
        // ============ NRM ROLE: per-batch raw normal sums -> ws + flag ============
        int b = blk - NRM_BASE;
        const float* rb = recon + (size_t)b * NV * 3;
        for (int j = tid; j < NV; j += 256) {
            sh.nrm.x[j] = rb[3*j]; sh.nrm.y[j] = rb[3*j+1]; sh.nrm.z[j] = rb[3*j+2];
            sh.nrm.vnx[j] = 0.0f; sh.nrm.vny[j] = 0.0f; sh.nrm.vnz[j] = 0.0f;
        }
        __syncthreads();
        for (int f = tid; f < NFACE; f += 256) {
            int i0 = faces[3*f], i1 = faces[3*f+1], i2 = faces[3*f+2];
            float p0x = sh.nrm.x[i0], p0y = sh.nrm.y[i0], p0z = sh.nrm.z[i0];
            float e1x = sh.nrm.x[i1] - p0x, e1y = sh.nrm.y[i1] - p0y, e1z = sh.nrm.z[i1] - p0z;
            float e2x = sh.nrm.x[i2] - p0x, e2y = sh.nrm.y[i2] - p0y, e2z = sh.nrm.z[i2] - p0z;
            float fx = e1y * e2z - e1z * e2y;
            float fy = e1z * e2x - e1x * e2z;
            float fz = e1x * e2y - e1y * e2x;
            atomicAdd(&sh.nrm.vnx[i0], fx); atomicAdd(&sh.nrm.vny[i0], fy); atomicAdd(&sh.nrm.vnz[i0], fz);
            atomicAdd(&sh.nrm.vnx[i1], fx); atomicAdd(&sh.nrm.vny[i1], fy); atomicAdd(&sh.nrm.vnz[i1], fz);
            atomicAdd(&sh.nrm.vnx[i2], fx); atomicAdd(&sh.nrm.vny[i2], fy); atomicAdd(&sh.nrm.vnz[i2], fz);
        }
        __syncthreads();
        float4* nrm4p = ws4 + (size_t)b * NVP;
        for (int j = tid; j < NVP; j += 256) {
            if (j < NV) {
                int src = c_perm.v[j];
                nrm4p[j] = make_float4(sh.nrm.vnx[src], sh.nrm.vny[src], sh.nrm.vnz[src], 0.0f);
            } else nrm4p[j] = make_float4(0.f, 0.f, 1.f, 0.0f);
        }
        __syncthreads();   // all nrm4p stores issued block-wide
        if (tid == 0) {
            __threadfence();  // publish nrm4p BYTES (non-atomic) before the flag
            __hip_atomic_store(&flags[256 + b], 1u, __ATOMIC_RELEASE, __HIP_MEMORY_SCOPE_AGENT);
        }
        if (b == 0) {
            // ---- param + KLD on the side (long before any consumer) ----
            if (tid < 2) s_pk[tid] = 0.0f;
            __syncthreads();
            float s_param = 0.0f, s_kld = 0.0f;
            for (int i = tid; i < NB * NPAR; i += 256) {
                float d = rp[i] - xp[i];
                s_param += d * d;
            }
            for (int i = tid; i < NB * NZ; i += 256) {
                float mv = mean[i], lv = log_var[i];
                s_kld += 1.0f + lv - mv * mv - expf(lv);
            }
            atomicAdd(&s_pk[0], s_param);
            atomicAdd(&s_pk[1], s_kld);
            __syncthreads();
            if (tid == 0) { atomicAdd(&acc[8], s_pk[0]); atomicAdd(&acc[9], s_pk[1]); }
        }
    }

    // ============ TICKET + FORMULA (vmcnt-ordered; no per-block L2 writeback) ============
    __syncthreads();   // block's global atomics all issued
    if (tid == 0) {
        asm volatile("s_waitcnt vmcnt(0)" ::: "memory");
        s_tk = atomicAdd((unsigned int*)&acc[15], 1u);
    }
    __syncthreads();
    if (s_tk == NBLOCKS - 1 && tid == 0) {
        __threadfence();                 // acquire (single block, negligible)
        const float fB = 64.0f;
        float a2v = __hip_atomic_load(&acc[2], __ATOMIC_RELAXED, __HIP_MEMORY_SCOPE_AGENT);
        float a3  = __hip_atomic_load(&acc[3], __ATOMIC_RELAXED, __HIP_MEMORY_SCOPE_AGENT);
        float a4  = __hip_atomic_load(&acc[4], __ATOMIC_RELAXED, __HIP_MEMORY_SCOPE_AGENT);
        float a5  = __hip_atomic_load(&acc[5], __ATOMIC_RELAXED, __HIP_MEMORY_SCOPE_AGENT);
        float a6  = __hip_atomic_load(&acc[6], __ATOMIC_RELAXED, __HIP_MEMORY_SCOPE_AGENT);
        float a7  = __hip_atomic_load(&acc[7], __ATOMIC_RELAXED, __HIP_MEMORY_SCOPE_AGENT);
        float a8  = __hip_atomic_load(&acc[8], __ATOMIC_RELAXED, __HIP_MEMORY_SCOPE_AGENT);
        float a9  = __hip_atomic_load(&acc[9], __ATOMIC_RELAXED, __HIP_MEMORY_SCOPE_AGENT);
        float param_loss  = a8 / fB;
        float KLD         = -0.5f * a9 / fB * 10.0f;
        float recon_loss  = a2v / fB;
        float cmap_loss   = 3000.0f * a3 / (fB * a4);
        float consistency = -5.0f * a6 / (a5 + 0.0001f);
        float penetr      = 100.0f * a7 / fB;
        out[0] = (recon_loss + KLD) + 0.1f * param_loss + 1000.0f * cmap_loss
               + 10.0f * consistency + 10.0f * penetr;
    }
}

extern "C" void kernel_launch(void* const* d_in, const int* in_sizes, int n_in,
                              void* d_out, int out_size, void* d_ws, size_t ws_size,
                              hipStream_t stream) {
    (void)in_sizes; (void)n_in; (void)out_size; (void)ws_size;
    const float* obj     = (const float*)d_in[0];
    const float* recon   = (const float*)d_in[1];
    const float* gt      = (const float*)d_in[2];
    const float* mean    = (const float*)d_in[3];
    const float* log_var = (const float*)d_in[4];
    const float* rp      = (const float*)d_in[5];
    const float* xp      = (const float*)d_in[6];
    const int*   faces   = (const int*)d_in[7];
    float* wsf = (float*)d_ws;
    float4* ws4 = (float4*)d_ws;
    float* acc = wsf + ACC_OFF;
    unsigned int* flags = (unsigned int*)(wsf + FLAGS_OFF);
    unsigned char* gcA  = (unsigned char*)(wsf + GC_OFF);
    float* out = (float*)d_out;

    hipMemsetAsync(acc, 0, (16 + NFLAGS) * sizeof(float), stream);
    k_all<<<NBLOCKS, 256, 0, stream>>>(obj, recon, gt, faces, mean, log_var,
                                       rp, xp, ws4, acc, flags, gcA, out);
}